// Round 14
// baseline (97.620 us; speedup 1.0000x reference)
//
#include <hip/hip_runtime.h>
#include <string.h>

#define NCRD 4096
#define NROW 8192
#define MT   32            // rows per block -> 256 blocks (1/CU)
#define WG_U4 114688       // total prepped weight size in uint4 (1.75 MB fp16)

typedef __attribute__((ext_vector_type(8)))  _Float16 half8;
typedef __attribute__((ext_vector_type(16))) float f32x16;
typedef __attribute__((ext_vector_type(4)))  int   i32x4;

static __device__ __forceinline__ float sinrev(float t){ return __builtin_amdgcn_sinf(__builtin_amdgcn_fractf(t)); }
static __device__ __forceinline__ float cosrev(float t){ return __builtin_amdgcn_cosf(__builtin_amdgcn_fractf(t)); }
static __device__ __forceinline__ unsigned short f2h(float f){   // RNE f32->fp16
    _Float16 h = (_Float16)f;
    unsigned short u; memcpy(&u, &h, 2); return u;
}

// Scheduler-opaque 16B global load. Ring discipline (R12/R13 lesson):
// with a PA/PD-slot ring, ALWAYS register-copy the current slot out before
// writing the prefetch into it — slot (c+P)%P aliases slot c%P.
static __device__ __forceinline__ i32x4 gload16(const uint4* p){
    i32x4 r;
    asm volatile("global_load_dwordx4 %0, %1, off" : "=v"(r) : "v"(p) : "memory");
    return r;
}
// Explicit vmcnt gate, data-tied to the two regs about to be consumed.
static __device__ __forceinline__ void vmwaitK(int K, i32x4& a, i32x4& b){
    if (K >= 16)      asm volatile("s_waitcnt vmcnt(16)" : "+v"(a), "+v"(b));
    else if (K >= 14) asm volatile("s_waitcnt vmcnt(14)" : "+v"(a), "+v"(b));
    else if (K >= 12) asm volatile("s_waitcnt vmcnt(12)" : "+v"(a), "+v"(b));
    else if (K >= 10) asm volatile("s_waitcnt vmcnt(10)" : "+v"(a), "+v"(b));
    else if (K >= 8)  asm volatile("s_waitcnt vmcnt(8)"  : "+v"(a), "+v"(b));
    else if (K >= 6)  asm volatile("s_waitcnt vmcnt(6)"  : "+v"(a), "+v"(b));
    else if (K >= 4)  asm volatile("s_waitcnt vmcnt(4)"  : "+v"(a), "+v"(b));
    else if (K >= 2)  asm volatile("s_waitcnt vmcnt(2)"  : "+v"(a), "+v"(b));
    else              asm volatile("s_waitcnt vmcnt(0)"  : "+v"(a), "+v"(b));
}

// Weight uint4 index within a layer (32x32x16 B-fragment layout):
//   idx = c*1024 + w*128 + hh*64 + lane
//   -> B[k = c*32 + hh*16 + (lane>>5)*8 + j][col = w*32 + (lane&31)], j=0..7.
// Sin layers (l even): terms {W, -W^3/6} stacked in k (K=512, 16 chunks).
// GEMM layers (l odd): W/(2pi) (K=256, 8 chunks).
__constant__ int c_offs[9] = {0,16384,24576,40960,49152,65536,73728,90112,98304};

// ---- prep: one coalesced uint4 store per thread; l==9: bias+coords --------
__global__ void prep_kernel(const float* __restrict__ w0, const float* __restrict__ ws,
                            const float* __restrict__ wlast, const float* __restrict__ w1,
                            const float* __restrict__ coords, const float* __restrict__ b1,
                            uint4* __restrict__ Wg, float* __restrict__ b1s,
                            float* __restrict__ out)
{
    int l = blockIdx.x, part = blockIdx.y, t = threadIdx.x;
    const float inv2pi = 0.15915494309189535f;
    if (l == 9) {
        int base = part*256 + t;                       // 0..16383
        if (base < 1024) b1s[base] = b1[base]*inv2pi;
        for (int i = base; i < NCRD*6; i += 16384)
            out[(size_t)NROW*256 + i] = coords[i];
        return;
    }
    bool sinl = !(l & 1);
    if (!sinl && part >= 32) return;                   // gemm layers: 8192 uint4
    const float* src;
    switch (l) {
        case 0: src = w0;          break;
        case 1: src = w1;          break;
        case 2: src = ws;          break;
        case 3: src = w1+65536;    break;
        case 4: src = ws+65536;    break;
        case 5: src = w1+2*65536;  break;
        case 6: src = ws+2*65536;  break;
        case 7: src = w1+3*65536;  break;
        default: src = wlast;      break;
    }
    int idx = part*256 + t;                 // uint4 index within layer
    int c  = idx >> 10, r = idx & 1023;
    int w  = r >> 7,  r2 = r & 127;
    int hh = r2 >> 6, ln = r2 & 63;
    int col  = w*32 + (ln & 31);
    int keff = c*32 + hh*16 + (ln >> 5)*8;
    int term = keff >> 8, kk = keff & 255;
    const float* s = src + col*256 + kk;    // 8 consecutive floats
    unsigned short h[8];
    #pragma unroll
    for (int j = 0; j < 8; ++j) {
        float wv_ = s[j], v;
        if (!sinl)          v = wv_ * inv2pi;
        else if (term == 0) v = wv_;
        else                v = -wv_*wv_*wv_*(1.0f/6.0f);
        h[j] = f2h(v);
    }
    uint4 o; memcpy(&o, h, 16);
    Wg[c_offs[l] + idx] = o;                // coalesced 16B store
}

// ---------------- one layer: 8 waves, 32x32 tile/wave ----------------------
// MODE: 0 = sin-layer (identity fp16 write), 1 = gemm (sin+x^3), 2 = last.
template<int MODE, int NC>
static __device__ __forceinline__ void do_layer(
    const uint4* __restrict__ wq,     // per-wave/lane weight base for this layer
    const float* __restrict__ br,     // bias row base (MODE 1)
    float* __restrict__ outg,         // global out (MODE 2)
    unsigned short* xa,
    int wv, int ls, int lm, int n0)   // ls = lane>>5, lm = lane&31
{
    constexpr int PD = 8;             // chunks in flight (16 x 1KB loads/wave)
    constexpr int RS = PD + 1;        // ring: consume slot != issue slot
    constexpr int PA = 2;             // A-fragment (LDS) prefetch depth
    f32x16 acc = {0.f,0.f,0.f,0.f,0.f,0.f,0.f,0.f,0.f,0.f,0.f,0.f,0.f,0.f,0.f,0.f};

    i32x4 ring0[RS], ring1[RS];
    #pragma unroll
    for (int p = 0; p < PD; ++p)      // prologue: issued before the barrier
        if (p < NC) {
            ring0[p % RS] = gload16(wq + p*1024);        // K-half 0
            ring1[p % RS] = gload16(wq + p*1024 + 64);   // K-half 1
        }

    __syncthreads();                  // prior xa writes visible
    const half8* xa8 = (const half8*)xa;
    half8 pa0[PA], pa1[PA];           // A frags: kb = c*4 + hh*2 + ls
    #pragma unroll
    for (int p = 0; p < PA; ++p) {
        pa0[p] = xa8[(p*4     + ls)*32 + lm];
        pa1[p] = xa8[(p*4 + 2 + ls)*32 + lm];
    }
    #pragma unroll
    for (int c = 0; c < NC; ++c) {
        // 1) issue next weight loads (feed VMEM pipe first)
        if (c + PD < NC) {
            ring0[(c+PD) % RS] = gload16(wq + (c+PD)*1024);
            ring1[(c+PD) % RS] = gload16(wq + (c+PD)*1024 + 64);
        }
        // 2) CONSUME-COPY the current A-slot before the prefetch overwrites it
        //    ((c+PA)%PA == c%PA — R12/R13 bug was writing first)
        half8 a0 = pa0[c % PA], a1 = pa1[c % PA];
        // 3) A-prefetch: ds_reads issued before parking at the vm gate
        if (c + PA < NC) {
            pa0[(c+PA) % PA] = xa8[((c+PA)*4     + ls)*32 + lm];
            pa1[(c+PA) % PA] = xa8[((c+PA)*4 + 2 + ls)*32 + lm];
        }
        // 4) gate on chunk c's weights
        int K = 2*(NC-1-c);
        vmwaitK(K > 16 ? 16 : K, ring0[c % RS], ring1[c % RS]);
        half8 b0, b1v;
        { i32x4 t0 = ring0[c % RS], t1 = ring1[c % RS];
          memcpy(&b0, &t0, 16); memcpy(&b1v, &t1, 16); }
        // 5) compute (acc-chained MFMAs pipeline fine: m119)
        acc = __builtin_amdgcn_mfma_f32_32x32x16_f16(a0, b0,  acc, 0,0,0);
        acc = __builtin_amdgcn_mfma_f32_32x32x16_f16(a1, b1v, acc, 0,0,0);
    }
    __syncthreads();                  // all xa reads done
    // ---- epilogue: C/D col=lane&31, row=(reg&3)+8*(reg>>2)+4*(lane>>5) ----
    float bb = 0.f;
    if (MODE == 1) bb = br[wv*32 + lm];
    int h = wv*32 + lm;
    #pragma unroll
    for (int r = 0; r < 16; ++r) {
        float v = acc[r];
        int m = (r & 3) + 8*(r >> 2) + 4*ls;
        if (MODE == 2) {
            outg[(size_t)(n0 + m)*256 + h] = v;
        } else if (MODE == 1) {
            float s = sinrev(v + bb);   // weights pre-scaled 1/2pi
            float s3 = s*s*s;
            xa[(((h>>3)     )*32 + m)*8 + (h&7)] = f2h(s);
            xa[(((h>>3) + 32)*32 + m)*8 + (h&7)] = f2h(s3);
        } else {
            xa[((h>>3)*32 + m)*8 + (h&7)] = f2h(v);
        }
    }
}

// ---------------- fused MFMA network kernel --------------------------------
// 512 threads = 8 waves, each owning a 32x32 tile via mfma_32x32x16_f16:
// halves the LDS A-read stream vs 16x16 tiling (16KB vs 32KB per chunk/CU).
__global__ __launch_bounds__(512, 2)
void net_kernel(const float* __restrict__ coords, const float* __restrict__ Bm,
                const uint4* __restrict__ Wg, const float* __restrict__ b1s,
                float* __restrict__ out)
{
    __shared__ unsigned short xa[64*32*8];    // 32KB activations [kb][m][k%8]
    __shared__ float cb[MT*3];
    __shared__ float bl[384];

    int tid = threadIdx.x, lane = tid & 63, wv = tid >> 6;   // wv 0..7
    int ls = (lane >> 5) & 1, lm = lane & 31;
    int n0 = blockIdx.x * MT;

    // ---- fourier features + x^3 powers -> xa ----
    for (int i = tid; i < MT*3; i += 512) {
        int r = i/3, d = i - 3*r, nv = n0 + r;
        cb[i] = (nv < NCRD) ? coords[nv*6 + d] : coords[(nv-NCRD)*6 + 3 + d];
    }
    for (int i = tid; i < 384; i += 512) bl[i] = Bm[i];
    __syncthreads();
    {
        int m = tid & 31, colb = (tid >> 5) * 16;       // 16 cols per thread
        float c0 = cb[m*3], c1 = cb[m*3+1], c2 = cb[m*3+2];
        unsigned short tmp[2][16];
        #pragma unroll
        for (int j = 0; j < 16; ++j) {
            int col = colb + j, f = col & 127;
            float p = c0*bl[f] + c1*bl[128+f] + c2*bl[256+f];   // 2pi cancels
            float s = (col < 128) ? sinrev(p) : cosrev(p);
            tmp[0][j] = f2h(s); tmp[1][j] = f2h(s*s*s);
        }
        #pragma unroll
        for (int pp = 0; pp < 2; ++pp)
            #pragma unroll
            for (int g = 0; g < 2; ++g) {
                uint4 v; memcpy(&v, &tmp[pp][g*8], 16);
                *(uint4*)&xa[((pp*32 + (colb>>3) + g)*32 + m)*8] = v;
            }
    }
    // (each do_layer's entry barrier orders xa writes before reads)

    int wl = wv*128 + lane;
    do_layer<0,16>(Wg +      0 + wl, nullptr,   nullptr, xa, wv, ls, lm, n0);
    do_layer<1, 8>(Wg +  16384 + wl, b1s + 0,   nullptr, xa, wv, ls, lm, n0);
    do_layer<0,16>(Wg +  24576 + wl, nullptr,   nullptr, xa, wv, ls, lm, n0);
    do_layer<1, 8>(Wg +  40960 + wl, b1s + 256, nullptr, xa, wv, ls, lm, n0);
    do_layer<0,16>(Wg +  49152 + wl, nullptr,   nullptr, xa, wv, ls, lm, n0);
    do_layer<1, 8>(Wg +  65536 + wl, b1s + 512, nullptr, xa, wv, ls, lm, n0);
    do_layer<0,16>(Wg +  73728 + wl, nullptr,   nullptr, xa, wv, ls, lm, n0);
    do_layer<1, 8>(Wg +  90112 + wl, b1s + 768, nullptr, xa, wv, ls, lm, n0);
    do_layer<2,16>(Wg +  98304 + wl, nullptr,   out,     xa, wv, ls, lm, n0);
}

// ---------------- launch ---------------------------------------------------
extern "C" void kernel_launch(void* const* d_in, const int* in_sizes, int n_in,
                              void* d_out, int out_size, void* d_ws, size_t ws_size,
                              hipStream_t stream)
{
    const float* coords = (const float*)d_in[0];
    const float* Bm     = (const float*)d_in[1];
    const float* w0     = (const float*)d_in[2];
    const float* ws     = (const float*)d_in[3];
    const float* wlast  = (const float*)d_in[4];
    const float* w1     = (const float*)d_in[5];
    const float* b1     = (const float*)d_in[6];
    float* out = (float*)d_out;

    uint4* Wg  = (uint4*)d_ws;                                   // 1.75 MB fp16
    float* b1s = (float*)((char*)d_ws + (size_t)WG_U4*16);       // 4 KB fp32

    dim3 pg(10, 64);
    prep_kernel<<<pg, 256, 0, stream>>>(w0, ws, wlast, w1, coords, b1, Wg, b1s, out);
    net_kernel<<<NROW/MT, 512, 0, stream>>>(coords, Bm, Wg, b1s, out);
}

// Round 15
// 96.912 us; speedup vs baseline: 1.0073x; 1.0073x over previous
//
#include <hip/hip_runtime.h>
#include <string.h>

#define NCRD 4096
#define NROW 8192
#define MT   32            // rows per block -> 256 blocks (1/CU)
#define WG_U4 114688       // total prepped weight size in uint4 (1.75 MB fp16)

typedef __attribute__((ext_vector_type(8)))  _Float16 half8;
typedef __attribute__((ext_vector_type(16))) float f32x16;
typedef __attribute__((ext_vector_type(4)))  int   i32x4;

static __device__ __forceinline__ float sinrev(float t){ return __builtin_amdgcn_sinf(__builtin_amdgcn_fractf(t)); }
static __device__ __forceinline__ float cosrev(float t){ return __builtin_amdgcn_cosf(__builtin_amdgcn_fractf(t)); }
static __device__ __forceinline__ unsigned short f2h(float f){   // RNE f32->fp16
    _Float16 h = (_Float16)f;
    unsigned short u; memcpy(&u, &h, 2); return u;
}

// Scheduler-opaque 16B global load. Ring discipline (R12/R13 lesson):
// always register-copy the current slot out before the prefetch overwrites it.
static __device__ __forceinline__ i32x4 gload16(const uint4* p){
    i32x4 r;
    asm volatile("global_load_dwordx4 %0, %1, off" : "=v"(r) : "v"(p) : "memory");
    return r;
}
// Explicit vmcnt gate, data-tied to the two regs about to be consumed.
static __device__ __forceinline__ void vmwaitK(int K, i32x4& a, i32x4& b){
    if (K >= 16)      asm volatile("s_waitcnt vmcnt(16)" : "+v"(a), "+v"(b));
    else if (K >= 14) asm volatile("s_waitcnt vmcnt(14)" : "+v"(a), "+v"(b));
    else if (K >= 12) asm volatile("s_waitcnt vmcnt(12)" : "+v"(a), "+v"(b));
    else if (K >= 10) asm volatile("s_waitcnt vmcnt(10)" : "+v"(a), "+v"(b));
    else if (K >= 8)  asm volatile("s_waitcnt vmcnt(8)"  : "+v"(a), "+v"(b));
    else if (K >= 6)  asm volatile("s_waitcnt vmcnt(6)"  : "+v"(a), "+v"(b));
    else if (K >= 4)  asm volatile("s_waitcnt vmcnt(4)"  : "+v"(a), "+v"(b));
    else if (K >= 2)  asm volatile("s_waitcnt vmcnt(2)"  : "+v"(a), "+v"(b));
    else              asm volatile("s_waitcnt vmcnt(0)"  : "+v"(a), "+v"(b));
}

// Weight uint4 index within a layer (32x32x16 B-fragment layout):
//   idx = c*1024 + w*128 + hh*64 + lane
//   -> B[k = c*32 + hh*16 + (lane>>5)*8 + j][col = w*32 + (lane&31)], j=0..7.
// Sin layers (l even): terms {W, -W^3/6} stacked in k (K=512, 16 chunks).
// GEMM layers (l odd): W/(2pi) (K=256, 8 chunks).
__constant__ int c_offs[9] = {0,16384,24576,40960,49152,65536,73728,90112,98304};

// ---- prep: one coalesced uint4 store per thread; l==9: bias+coords --------
__global__ void prep_kernel(const float* __restrict__ w0, const float* __restrict__ ws,
                            const float* __restrict__ wlast, const float* __restrict__ w1,
                            const float* __restrict__ coords, const float* __restrict__ b1,
                            uint4* __restrict__ Wg, float* __restrict__ b1s,
                            float* __restrict__ out)
{
    int l = blockIdx.x, part = blockIdx.y, t = threadIdx.x;
    const float inv2pi = 0.15915494309189535f;
    if (l == 9) {
        int base = part*256 + t;                       // 0..16383
        if (base < 1024) b1s[base] = b1[base]*inv2pi;
        for (int i = base; i < NCRD*6; i += 16384)
            out[(size_t)NROW*256 + i] = coords[i];
        return;
    }
    bool sinl = !(l & 1);
    if (!sinl && part >= 32) return;                   // gemm layers: 8192 uint4
    const float* src;
    switch (l) {
        case 0: src = w0;          break;
        case 1: src = w1;          break;
        case 2: src = ws;          break;
        case 3: src = w1+65536;    break;
        case 4: src = ws+65536;    break;
        case 5: src = w1+2*65536;  break;
        case 6: src = ws+2*65536;  break;
        case 7: src = w1+3*65536;  break;
        default: src = wlast;      break;
    }
    int idx = part*256 + t;                 // uint4 index within layer
    int c  = idx >> 10, r = idx & 1023;
    int w  = r >> 7,  r2 = r & 127;
    int hh = r2 >> 6, ln = r2 & 63;
    int col  = w*32 + (ln & 31);
    int keff = c*32 + hh*16 + (ln >> 5)*8;
    int term = keff >> 8, kk = keff & 255;
    const float* s = src + col*256 + kk;    // 8 consecutive floats
    unsigned short h[8];
    #pragma unroll
    for (int j = 0; j < 8; ++j) {
        float wv_ = s[j], v;
        if (!sinl)          v = wv_ * inv2pi;
        else if (term == 0) v = wv_;
        else                v = -wv_*wv_*wv_*(1.0f/6.0f);
        h[j] = f2h(v);
    }
    uint4 o; memcpy(&o, h, 16);
    Wg[c_offs[l] + idx] = o;                // coalesced 16B store
}

// ---------------- one layer: 8 waves, 32x32 tile/wave, phase-skewed --------
// MODE: 0 = sin-layer (identity fp16 write), 1 = gemm (sin+x^3), 2 = last.
// Chunks are processed in rotated order (c+ph)%NC: K-chunks commute, and the
// rotation de-correlates the 32 same-XCD CUs' L2 address streams so requests
// spread across all L2 channels instead of piling on the same 4.
template<int MODE, int NC>
static __device__ __forceinline__ void do_layer(
    const uint4* __restrict__ wq,     // per-wave/lane weight base for this layer
    const float* __restrict__ br,     // bias row base (MODE 1)
    float* __restrict__ outg,         // global out (MODE 2)
    unsigned short* xa,
    int wv, int ls, int lm, int n0, int ph)
{
    constexpr int PD = 8;             // chunks in flight (16 x 1KB loads/wave)
    constexpr int RS = PD + 1;        // ring: consume slot != issue slot
    constexpr int PA = 2;             // A-fragment (LDS) prefetch depth
    constexpr int CM = NC - 1;        // NC is a power of 2
    f32x16 acc = {0.f,0.f,0.f,0.f,0.f,0.f,0.f,0.f,0.f,0.f,0.f,0.f,0.f,0.f,0.f,0.f};

    i32x4 ring0[RS], ring1[RS];
    #pragma unroll
    for (int p = 0; p < PD; ++p)      // prologue: issued before the barrier
        if (p < NC) {
            int ci = (p + ph) & CM;
            ring0[p % RS] = gload16(wq + ci*1024);        // K-half 0
            ring1[p % RS] = gload16(wq + ci*1024 + 64);   // K-half 1
        }

    __syncthreads();                  // prior xa writes visible
    const half8* xa8 = (const half8*)xa;
    half8 pa0[PA], pa1[PA];           // A frags: kb = ci*4 + hh*2 + ls
    #pragma unroll
    for (int p = 0; p < PA; ++p) {
        int ci = (p + ph) & CM;
        pa0[p] = xa8[(ci*4     + ls)*32 + lm];
        pa1[p] = xa8[(ci*4 + 2 + ls)*32 + lm];
    }
    #pragma unroll
    for (int c = 0; c < NC; ++c) {
        // 1) issue next weight loads (feed VMEM pipe first)
        if (c + PD < NC) {
            int ci = (c + PD + ph) & CM;
            ring0[(c+PD) % RS] = gload16(wq + ci*1024);
            ring1[(c+PD) % RS] = gload16(wq + ci*1024 + 64);
        }
        // 2) consume-copy current A-slot BEFORE the prefetch overwrites it
        half8 a0 = pa0[c % PA], a1 = pa1[c % PA];
        // 3) A-prefetch for logical chunk c+PA (rotated address)
        if (c + PA < NC) {
            int ci = (c + PA + ph) & CM;
            pa0[(c+PA) % PA] = xa8[(ci*4     + ls)*32 + lm];
            pa1[(c+PA) % PA] = xa8[(ci*4 + 2 + ls)*32 + lm];
        }
        // 4) gate on chunk c's weights
        int K = 2*(NC-1-c);
        vmwaitK(K > 16 ? 16 : K, ring0[c % RS], ring1[c % RS]);
        half8 b0, b1v;
        { i32x4 t0 = ring0[c % RS], t1 = ring1[c % RS];
          memcpy(&b0, &t0, 16); memcpy(&b1v, &t1, 16); }
        // 5) compute
        acc = __builtin_amdgcn_mfma_f32_32x32x16_f16(a0, b0,  acc, 0,0,0);
        acc = __builtin_amdgcn_mfma_f32_32x32x16_f16(a1, b1v, acc, 0,0,0);
    }
    __syncthreads();                  // all xa reads done
    // ---- epilogue: C/D col=lane&31, row=(reg&3)+8*(reg>>2)+4*(lane>>5) ----
    float bb = 0.f;
    if (MODE == 1) bb = br[wv*32 + lm];
    int h = wv*32 + lm;
    #pragma unroll
    for (int r = 0; r < 16; ++r) {
        float v = acc[r];
        int m = (r & 3) + 8*(r >> 2) + 4*ls;
        if (MODE == 2) {
            outg[(size_t)(n0 + m)*256 + h] = v;
        } else if (MODE == 1) {
            float s = sinrev(v + bb);   // weights pre-scaled 1/2pi
            float s3 = s*s*s;
            xa[(((h>>3)     )*32 + m)*8 + (h&7)] = f2h(s);
            xa[(((h>>3) + 32)*32 + m)*8 + (h&7)] = f2h(s3);
        } else {
            xa[((h>>3)*32 + m)*8 + (h&7)] = f2h(v);
        }
    }
}

// ---------------- fused MFMA network kernel --------------------------------
__global__ __launch_bounds__(512, 2)
void net_kernel(const float* __restrict__ coords, const float* __restrict__ Bm,
                const uint4* __restrict__ Wg, const float* __restrict__ b1s,
                float* __restrict__ out)
{
    __shared__ unsigned short xa[64*32*8];    // 32KB activations [kb][m][k%8]
    __shared__ float cb[MT*3];
    __shared__ float bl[384];

    int tid = threadIdx.x, lane = tid & 63, wv = tid >> 6;   // wv 0..7
    int ls = (lane >> 5) & 1, lm = lane & 31;
    int n0 = blockIdx.x * MT;
    // Consecutive same-XCD blocks (b, b+8, b+16, ...) get consecutive phases.
    int ph = (int)(blockIdx.x >> 3);

    // ---- fourier features + x^3 powers -> xa ----
    for (int i = tid; i < MT*3; i += 512) {
        int r = i/3, d = i - 3*r, nv = n0 + r;
        cb[i] = (nv < NCRD) ? coords[nv*6 + d] : coords[(nv-NCRD)*6 + 3 + d];
    }
    for (int i = tid; i < 384; i += 512) bl[i] = Bm[i];
    __syncthreads();
    {
        int m = tid & 31, colb = (tid >> 5) * 16;       // 16 cols per thread
        float c0 = cb[m*3], c1 = cb[m*3+1], c2 = cb[m*3+2];
        unsigned short tmp[2][16];
        #pragma unroll
        for (int j = 0; j < 16; ++j) {
            int col = colb + j, f = col & 127;
            float p = c0*bl[f] + c1*bl[128+f] + c2*bl[256+f];   // 2pi cancels
            float s = (col < 128) ? sinrev(p) : cosrev(p);
            tmp[0][j] = f2h(s); tmp[1][j] = f2h(s*s*s);
        }
        #pragma unroll
        for (int pp = 0; pp < 2; ++pp)
            #pragma unroll
            for (int g = 0; g < 2; ++g) {
                uint4 v; memcpy(&v, &tmp[pp][g*8], 16);
                *(uint4*)&xa[((pp*32 + (colb>>3) + g)*32 + m)*8] = v;
            }
    }
    // (each do_layer's entry barrier orders xa writes before reads)

    int wl = wv*128 + lane;
    do_layer<0,16>(Wg +      0 + wl, nullptr,   nullptr, xa, wv, ls, lm, n0, ph);
    do_layer<1, 8>(Wg +  16384 + wl, b1s + 0,   nullptr, xa, wv, ls, lm, n0, ph);
    do_layer<0,16>(Wg +  24576 + wl, nullptr,   nullptr, xa, wv, ls, lm, n0, ph);
    do_layer<1, 8>(Wg +  40960 + wl, b1s + 256, nullptr, xa, wv, ls, lm, n0, ph);
    do_layer<0,16>(Wg +  49152 + wl, nullptr,   nullptr, xa, wv, ls, lm, n0, ph);
    do_layer<1, 8>(Wg +  65536 + wl, b1s + 512, nullptr, xa, wv, ls, lm, n0, ph);
    do_layer<0,16>(Wg +  73728 + wl, nullptr,   nullptr, xa, wv, ls, lm, n0, ph);
    do_layer<1, 8>(Wg +  90112 + wl, b1s + 768, nullptr, xa, wv, ls, lm, n0, ph);
    do_layer<2,16>(Wg +  98304 + wl, nullptr,   out,     xa, wv, ls, lm, n0, ph);
}

// ---------------- launch ---------------------------------------------------
extern "C" void kernel_launch(void* const* d_in, const int* in_sizes, int n_in,
                              void* d_out, int out_size, void* d_ws, size_t ws_size,
                              hipStream_t stream)
{
    const float* coords = (const float*)d_in[0];
    const float* Bm     = (const float*)d_in[1];
    const float* w0     = (const float*)d_in[2];
    const float* ws     = (const float*)d_in[3];
    const float* wlast  = (const float*)d_in[4];
    const float* w1     = (const float*)d_in[5];
    const float* b1     = (const float*)d_in[6];
    float* out = (float*)d_out;

    uint4* Wg  = (uint4*)d_ws;                                   // 1.75 MB fp16
    float* b1s = (float*)((char*)d_ws + (size_t)WG_U4*16);       // 4 KB fp32

    dim3 pg(10, 64);
    prep_kernel<<<pg, 256, 0, stream>>>(w0, ws, wlast, w1, coords, b1, Wg, b1s, out);
    net_kernel<<<NROW/MT, 512, 0, stream>>>(coords, Bm, Wg, b1s, out);
}